// Round 1
// 429.525 us; speedup vs baseline: 1.0535x; 1.0535x over previous
//
#include <hip/hip_runtime.h>

#define SLOPE 0.01f
#define EPSB 1e-5f
#define INV_CNT (1.0f/131072.0f)

typedef unsigned short u16;
typedef unsigned int u32;
typedef __attribute__((ext_vector_type(8))) short s16x8;
typedef __attribute__((ext_vector_type(4))) float f4;

__device__ float g_stats[3][2][128];   // [which][sum|sq][channel]
__device__ float g_sb[3][2][128];      // [which][scale|bias][channel]
__device__ float g_part[2048][256];    // per-block partial stats [block][sum128|sq128]
__device__ u16 g_w1h[3][128][64];      // [k][co][ci] hi
__device__ u16 g_w1l[3][128][64];      // lo
__device__ u16 g_w2h[3][128][128];
__device__ u16 g_w2l[3][128][128];
__device__ u16 g_wmh[128][128];        // [e][d]
__device__ u16 g_wml[128][128];
__device__ u16 g_wqh[128][128];        // theta
__device__ u16 g_wql[128][128];

__device__ __forceinline__ float lrelu(float x){ return x > 0.f ? x : SLOPE*x; }
__device__ __forceinline__ u16 f2b(float f){
  u32 u = __float_as_uint(f);
  return (u16)((u + 0x7fffu + ((u >> 16) & 1u)) >> 16);   // RNE
}
__device__ __forceinline__ float b2f(u16 h){ return __uint_as_float(((u32)h) << 16); }
__device__ __forceinline__ u32 pk(float a, float b){ return (u32)f2b(a) | ((u32)f2b(b) << 16); }
__device__ __forceinline__ u32 pkhl(float f){
  u16 h = f2b(f);
  u16 l = f2b(f - b2f(h));
  return (u32)h | ((u32)l << 16);
}
__device__ __forceinline__ float unhl(u32 v){ return b2f((u16)(v & 0xffff)) + b2f((u16)(v >> 16)); }

// ---------------- zero stats ----------------
__global__ void k_zero(){
  int i = blockIdx.x*256 + threadIdx.x;
  if (i < 768) ((float*)g_stats)[i] = 0.f;
}

// ---------------- reduce per-block partials -> g_stats[which] ----------------
__global__ void k_reduce(int which){
  const float* base = &g_part[blockIdx.x*128][0];
  int j = threadIdx.x;
  float s = 0.f;
  #pragma unroll 4
  for (int r = 0; r < 128; ++r) s += base[r*256 + j];
  atomicAdd(&((float*)g_stats)[which*256 + j], s);
}

// ---------------- prep: fp32 weights -> bf16 hi/lo device globals ----------------
__global__ void k_prepw(const float* __restrict__ w1, const float* __restrict__ w2,
                        const float* __restrict__ mapw, const float* __restrict__ thw){
  int idx = blockIdx.x*256 + threadIdx.x;
  if (idx < 24576){
    int kk = idx >> 13, r = idx & 8191, co = r >> 6, ci = r & 63;
    float v = w1[co*192 + ci*3 + kk];
    u16 h = f2b(v);
    g_w1h[kk][co][ci] = h; g_w1l[kk][co][ci] = f2b(v - b2f(h));
  } else if (idx < 73728){
    int j = idx - 24576;
    int kk = j >> 14, r = j & 16383, co = r >> 7, ci = r & 127;
    float v = w2[co*384 + ci*3 + kk];
    u16 h = f2b(v);
    g_w2h[kk][co][ci] = h; g_w2l[kk][co][ci] = f2b(v - b2f(h));
  } else if (idx < 90112){
    int j = idx - 73728;
    float v = mapw[j];
    u16 h = f2b(v);
    ((u16*)g_wmh)[j] = h; ((u16*)g_wml)[j] = f2b(v - b2f(h));
  } else if (idx < 106496){
    int j = idx - 90112;
    float v = thw[j];
    u16 h = f2b(v);
    ((u16*)g_wqh)[j] = h; ((u16*)g_wql)[j] = f2b(v - b2f(h));
  }
}

// ---------------- finalize BN stats -> scale/bias ----------------
__global__ void k_finalize(const float* __restrict__ g, const float* __restrict__ bta, int which){
  int c = threadIdx.x;   // 128
  float mean = g_stats[which][0][c] * INV_CNT;
  float var  = g_stats[which][1][c] * INV_CNT - mean*mean;
  float sc = g[c] * rsqrtf(var + EPSB);
  g_sb[which][0][c] = sc;
  g_sb[which][1][c] = bta[c] - mean*sc;
}

// ---------------- conv1 MFMA: x[b,t,n,64] -> y1hl[bn][t][co][h|l] pairs, BN1 partials ----------------
__global__ __launch_bounds__(256) void k_conv1(const float* __restrict__ x, u16* __restrict__ y1hl){
  __shared__ __align__(16) u16 a0h[2][34][72];
  __shared__ __align__(16) u16 a0l[2][34][72];
  __shared__ __align__(16) u16 w1s[128][72];
  const int bid = blockIdx.x;
  const int bn0 = bid*2;
  const int b = bn0 >> 8, n = bn0 & 255;
  const int tid = threadIdx.x;
  const int w = tid >> 6, l = tid & 63, quad = l >> 4, lm = l & 15;
  f4 acc[2][4];
  #pragma unroll
  for (int i = 0; i < 2; ++i)
    #pragma unroll
    for (int j = 0; j < 4; ++j) acc[i][j] = (f4)0.f;

  { // stage x -> a0h/a0l (hi/lo bf16), transposed to [t][ci]
    int nn = tid >> 7, rem = tid & 127, t = rem >> 2, ci0 = (rem & 3)*16;
    const float* px = x + ((b*32 + t)*256 + n + nn)*64 + ci0;
    u16 hh[16], ll[16];
    #pragma unroll
    for (int j = 0; j < 4; ++j){
      float4 v = *(const float4*)(px + 4*j);
      float vv[4] = {v.x, v.y, v.z, v.w};
      #pragma unroll
      for (int e = 0; e < 4; ++e){
        u16 h = f2b(vv[e]);
        hh[4*j+e] = h; ll[4*j+e] = f2b(vv[e] - b2f(h));
      }
    }
    *(uint4*)&a0h[nn][t+1][ci0]   = *(uint4*)&hh[0];
    *(uint4*)&a0h[nn][t+1][ci0+8] = *(uint4*)&hh[8];
    *(uint4*)&a0l[nn][t+1][ci0]   = *(uint4*)&ll[0];
    *(uint4*)&a0l[nn][t+1][ci0+8] = *(uint4*)&ll[8];
  }
  for (int u = tid; u < 288; u += 256){
    int a = u / 144, rr = u % 144, r = rr / 36, cw = rr % 36;
    u32* base = a ? (u32*)&a0l[r>>1][(r&1)*33][0] : (u32*)&a0h[r>>1][(r&1)*33][0];
    base[cw] = 0u;
  }

  for (int kk = 0; kk < 3; ++kk){
    // pass 0: hi weights, terms Hw*Hx + Hw*Lx
    __syncthreads();
    { int co = tid >> 1, c0 = (tid & 1)*32;
      #pragma unroll
      for (int j = 0; j < 4; ++j)
        *(uint4*)&w1s[co][c0 + 8*j] = *(const uint4*)&g_w1h[kk][co][c0 + 8*j];
    }
    __syncthreads();
    #pragma unroll
    for (int s = 0; s < 2; ++s){
      int ci0 = s*32 + quad*8;
      s16x8 af[2], bh[4], bl[4];
      #pragma unroll
      for (int i = 0; i < 2; ++i) af[i] = *(s16x8*)&w1s[(2*w+i)*16 + lm][ci0];
      #pragma unroll
      for (int nt = 0; nt < 4; ++nt){
        bh[nt] = *(s16x8*)&a0h[nt>>1][(nt&1)*16 + lm + kk][ci0];
        bl[nt] = *(s16x8*)&a0l[nt>>1][(nt&1)*16 + lm + kk][ci0];
      }
      #pragma unroll
      for (int i = 0; i < 2; ++i)
        #pragma unroll
        for (int nt = 0; nt < 4; ++nt){
          acc[i][nt] = __builtin_amdgcn_mfma_f32_16x16x32_bf16(af[i], bh[nt], acc[i][nt], 0, 0, 0);
          acc[i][nt] = __builtin_amdgcn_mfma_f32_16x16x32_bf16(af[i], bl[nt], acc[i][nt], 0, 0, 0);
        }
    }
    // pass 1: lo weights, term Lw*Hx
    __syncthreads();
    { int co = tid >> 1, c0 = (tid & 1)*32;
      #pragma unroll
      for (int j = 0; j < 4; ++j)
        *(uint4*)&w1s[co][c0 + 8*j] = *(const uint4*)&g_w1l[kk][co][c0 + 8*j];
    }
    __syncthreads();
    #pragma unroll
    for (int s = 0; s < 2; ++s){
      int ci0 = s*32 + quad*8;
      s16x8 af[2], bh[4];
      #pragma unroll
      for (int i = 0; i < 2; ++i) af[i] = *(s16x8*)&w1s[(2*w+i)*16 + lm][ci0];
      #pragma unroll
      for (int nt = 0; nt < 4; ++nt) bh[nt] = *(s16x8*)&a0h[nt>>1][(nt&1)*16 + lm + kk][ci0];
      #pragma unroll
      for (int i = 0; i < 2; ++i)
        #pragma unroll
        for (int nt = 0; nt < 4; ++nt)
          acc[i][nt] = __builtin_amdgcn_mfma_f32_16x16x32_bf16(af[i], bh[nt], acc[i][nt], 0, 0, 0);
    }
  }
  #pragma unroll
  for (int i = 0; i < 2; ++i){
    int co0 = (2*w+i)*16 + quad*4;
    float s0=0,s1=0,s2=0,s3=0,q0=0,q1=0,q2=0,q3=0;
    #pragma unroll
    for (int nt = 0; nt < 4; ++nt){
      f4 a = acc[i][nt];
      int nn = nt >> 1, t = (nt & 1)*16 + lm;
      uint4 p;
      p.x = pkhl(a.x); p.y = pkhl(a.y); p.z = pkhl(a.z); p.w = pkhl(a.w);
      *(uint4*)&y1hl[(((bn0+nn)*32 + t)*128 + co0)*2] = p;
      s0+=a.x; s1+=a.y; s2+=a.z; s3+=a.w;
      q0+=a.x*a.x; q1+=a.y*a.y; q2+=a.z*a.z; q3+=a.w*a.w;
    }
    #pragma unroll
    for (int m = 1; m < 16; m <<= 1){
      s0+=__shfl_xor(s0,m); s1+=__shfl_xor(s1,m); s2+=__shfl_xor(s2,m); s3+=__shfl_xor(s3,m);
      q0+=__shfl_xor(q0,m); q1+=__shfl_xor(q1,m); q2+=__shfl_xor(q2,m); q3+=__shfl_xor(q3,m);
    }
    if (lm == 0){
      f4 sv = {s0,s1,s2,s3}, qv = {q0,q1,q2,q3};
      *(f4*)&g_part[bid][co0]       = sv;
      *(f4*)&g_part[bid][128 + co0] = qv;
    }
  }
}

// ---------------- conv2 MFMA: bn1+relu(exact y1) -> spa (permuted, bf16, pre-BN2), BN2 partials ----------------
__global__ __launch_bounds__(256) void k_conv2(const u16* __restrict__ y1hl, u16* __restrict__ spa){
  __shared__ __align__(16) u16 a1s[2][34][136];
  __shared__ __align__(16) u16 w2s[128][136];
  const int bid = blockIdx.x;
  const int bn0 = bid*2;
  const int b = bn0 >> 8, n = bn0 & 255;
  const int tid = threadIdx.x;
  const int w = tid >> 6, l = tid & 63, quad = l >> 4, lm = l & 15;
  f4 acc2[4][2];
  #pragma unroll
  for (int mt = 0; mt < 4; ++mt)
    #pragma unroll
    for (int i = 0; i < 2; ++i) acc2[mt][i] = (f4)0.f;

  { // stage bn1+relu(exact y1) -> a1s
    int nn = tid >> 7, rem = tid & 127, t = rem >> 2, ci0 = (rem & 3)*32;
    const u16* py = y1hl + (((bn0+nn)*32 + t)*128)*2;
    #pragma unroll
    for (int j = 0; j < 4; ++j){
      uint4 va = *(const uint4*)&py[(ci0 + 8*j)*2];
      uint4 vb = *(const uint4*)&py[(ci0 + 8*j + 4)*2];
      u32 vv[8] = {va.x, va.y, va.z, va.w, vb.x, vb.y, vb.z, vb.w};
      u16 oo[8];
      #pragma unroll
      for (int e = 0; e < 8; ++e){
        int ci = ci0 + 8*j + e;
        float f = fmaxf(fmaf(unhl(vv[e]), g_sb[0][0][ci], g_sb[0][1][ci]), 0.f);
        oo[e] = f2b(f);
      }
      *(uint4*)&a1s[nn][t+1][ci0 + 8*j] = *(uint4*)&oo[0];
    }
  }
  for (int u = tid; u < 272; u += 256){
    int r = u/68, cw = u%68;
    ((u32*)&a1s[r>>1][(r&1)*33][0])[cw] = 0u;
  }

  for (int kk = 0; kk < 3; ++kk){
    #pragma unroll
    for (int pass = 0; pass < 2; ++pass){
      __syncthreads();
      { int co = tid >> 1, c0 = (tid & 1)*64;
        const u16* src = pass ? &g_w2l[kk][co][0] : &g_w2h[kk][co][0];
        #pragma unroll
        for (int j = 0; j < 8; ++j)
          *(uint4*)&w2s[co][c0 + 8*j] = *(const uint4*)&src[c0 + 8*j];
      }
      __syncthreads();
      #pragma unroll
      for (int s = 0; s < 4; ++s){
        int ci0 = s*32 + quad*8;
        s16x8 ax[4], bw[2];
        #pragma unroll
        for (int mt = 0; mt < 4; ++mt) ax[mt] = *(s16x8*)&a1s[mt>>1][(mt&1)*16 + lm + kk][ci0];
        #pragma unroll
        for (int i = 0; i < 2; ++i) bw[i] = *(s16x8*)&w2s[(2*w+i)*16 + lm][ci0];
        #pragma unroll
        for (int mt = 0; mt < 4; ++mt)
          #pragma unroll
          for (int i = 0; i < 2; ++i)
            acc2[mt][i] = __builtin_amdgcn_mfma_f32_16x16x32_bf16(ax[mt], bw[i], acc2[mt][i], 0, 0, 0);
      }
    }
  }
  #pragma unroll
  for (int i = 0; i < 2; ++i){
    int co = (2*w+i)*16 + lm;
    float s = 0.f, q = 0.f;
    #pragma unroll
    for (int mt = 0; mt < 4; ++mt){
      f4 a = acc2[mt][i];
      int off0 = co*32 + (mt&1)*16 + quad*4;       // off = co*32 + t
      int tp = off0 >> 7, cp = off0 & 127;
      int row = (b*32 + tp)*256 + (n + (mt>>1));
      uint2 p; p.x = pk(a.x, a.y); p.y = pk(a.z, a.w);
      *(uint2*)&spa[row*128 + cp] = p;
      s += a.x + a.y + a.z + a.w;
      q += a.x*a.x + a.y*a.y + a.z*a.z + a.w*a.w;
    }
    s += __shfl_xor(s, 16); s += __shfl_xor(s, 32);
    q += __shfl_xor(q, 16); q += __shfl_xor(q, 32);
    if (l < 16){
      g_part[bid][co]       = s;
      g_part[bid][128 + co] = q;
    }
  }
}

// ---------------- in-place BN2 + relu on spa ----------------
__global__ void k_act(u16* __restrict__ spa){
  int idx = blockIdx.x*256 + threadIdx.x;
  int flat = idx*8;
  int cp0 = flat & 127;
  int row = flat >> 7;
  int bpp = row >> 8;
  int tp = bpp & 31;
  int c = (tp*128 + cp0) >> 5;
  float sc = g_sb[1][0][c], bi = g_sb[1][1][c];
  uint4 v = *(uint4*)(spa + flat);
  u16 h[8]; *(uint4*)&h[0] = v;
  u16 o[8];
  #pragma unroll
  for (int i = 0; i < 8; ++i) o[i] = f2b(fmaxf(fmaf(b2f(h[i]), sc, bi), 0.f));
  *(uint4*)(spa + flat) = *(uint4*)&o[0];
}

// ---------------- gemm128 MFMA: out[r][e] = sum_d A[r][d]*W[e][d] + b[e], W two-pass hi/lo ----------------
// wsel=0 (map): write hi/lo bf16 planes chunked mh/ml[(bp*4+dc)*256+m][32]; wsel=1 (theta): fp32 + stats
__global__ __launch_bounds__(256) void k_gemm128b(const u16* __restrict__ A,
                                                  const float* __restrict__ bvec,
                                                  void* __restrict__ outv,
                                                  int wsel, int do_stats){
  __shared__ __align__(16) u16 As[64][136];
  __shared__ __align__(16) u16 Ws[128][136];
  const u16* Wh = wsel ? &g_wqh[0][0] : &g_wmh[0][0];
  const u16* Wl = wsel ? &g_wql[0][0] : &g_wml[0][0];
  const int bid = blockIdx.x;
  const int rowbase = bid * 64;
  const int tid = threadIdx.x;
  const int w = tid >> 6, l = tid & 63, quad = l >> 4, lm = l & 15;
  f4 acc[2][4];
  #pragma unroll
  for (int i = 0; i < 2; ++i)
    #pragma unroll
    for (int rt = 0; rt < 4; ++rt) acc[i][rt] = (f4)0.f;

  { int r = tid >> 2, c0 = (tid & 3)*32;
    #pragma unroll
    for (int j = 0; j < 4; ++j)
      *(uint4*)&As[r][c0 + 8*j] = *(const uint4*)&A[(rowbase + r)*128 + c0 + 8*j];
  }
  #pragma unroll
  for (int pass = 0; pass < 2; ++pass){
    if (pass) __syncthreads();
    { int e = tid >> 1, c0 = (tid & 1)*64;
      const u16* src = (pass ? Wl : Wh) + e*128;
      #pragma unroll
      for (int j = 0; j < 8; ++j)
        *(uint4*)&Ws[e][c0 + 8*j] = *(const uint4*)&src[c0 + 8*j];
    }
    __syncthreads();
    #pragma unroll
    for (int s = 0; s < 4; ++s){
      int k0 = s*32 + quad*8;
      s16x8 aw[2], ba[4];
      #pragma unroll
      for (int i = 0; i < 2; ++i) aw[i] = *(s16x8*)&Ws[(2*w+i)*16 + lm][k0];
      #pragma unroll
      for (int rt = 0; rt < 4; ++rt) ba[rt] = *(s16x8*)&As[rt*16 + lm][k0];
      #pragma unroll
      for (int i = 0; i < 2; ++i)
        #pragma unroll
        for (int rt = 0; rt < 4; ++rt)
          acc[i][rt] = __builtin_amdgcn_mfma_f32_16x16x32_bf16(aw[i], ba[rt], acc[i][rt], 0, 0, 0);
    }
    if (!pass) __syncthreads();   // all reads done before Ws restage
  }
  #pragma unroll
  for (int i = 0; i < 2; ++i){
    int e0 = (2*w+i)*16 + quad*4;
    f4 bv = *(const f4*)&bvec[e0];
    if (wsel == 0){
      // mapped mode: hi/lo planes, chunked [bp][dc][m][32]
      u16* mh = (u16*)outv;
      u16* ml = mh + 16777216;
      int dc = e0 >> 5, ec = e0 & 31;
      #pragma unroll
      for (int rt = 0; rt < 4; ++rt){
        int row = rowbase + rt*16 + lm;
        int bp = row >> 8, m = row & 255;
        f4 o = acc[i][rt] + bv;
        float fv[4] = {o.x, o.y, o.z, o.w};
        u16 hh[4], ll[4];
        #pragma unroll
        for (int e = 0; e < 4; ++e){
          u16 h = f2b(fv[e]);
          hh[e] = h; ll[e] = f2b(fv[e] - b2f(h));
        }
        int off = ((bp*4 + dc)*256 + m)*32 + ec;
        *(uint2*)&mh[off] = *(uint2*)&hh[0];
        *(uint2*)&ml[off] = *(uint2*)&ll[0];
      }
    } else {
      float* outp = (float*)outv;
      f4 sv = (f4)0.f, qv = (f4)0.f;
      #pragma unroll
      for (int rt = 0; rt < 4; ++rt){
        int row = rowbase + rt*16 + lm;
        f4 o = acc[i][rt] + bv;
        *(f4*)&outp[row*128 + e0] = o;
        sv += o; qv += o*o;
      }
      if (do_stats){
        #pragma unroll
        for (int m = 1; m < 16; m <<= 1){
          sv.x+=__shfl_xor(sv.x,m); sv.y+=__shfl_xor(sv.y,m); sv.z+=__shfl_xor(sv.z,m); sv.w+=__shfl_xor(sv.w,m);
          qv.x+=__shfl_xor(qv.x,m); qv.y+=__shfl_xor(qv.y,m); qv.z+=__shfl_xor(qv.z,m); qv.w+=__shfl_xor(qv.w,m);
        }
        if (lm == 0){
          *(f4*)&g_part[bid][e0]       = sv;
          *(f4*)&g_part[bid][128 + e0] = qv;
        }
      }
    }
  }
}

// ---------------- fused adj+agg MFMA, mapped pre-split hi/lo planes ----------------
__global__ __launch_bounds__(256) void k_adjagg(const u16* __restrict__ mh,
                                                const u16* __restrict__ ml,
                                                const u16* __restrict__ spa,
                                                u16* __restrict__ agg){
  __shared__ __align__(16) char smem[52224];
  u16 (*mbh)[40]   = (u16(*)[40])(smem);
  u16 (*mbl)[40]   = (u16(*)[40])(smem + 20480);
  u16 (*Ps)[264]   = (u16(*)[264])(smem);            // [64][264] = 33792 B
  u16 (*spasT)[72] = (u16(*)[72])(smem + 33792);     // [128][72] = 18432 B
  // XCD-aware remap: 4 nt-blocks of one bp land consecutively on the same XCD
  const int rb = blockIdx.x;
  const int vb = (rb & 7)*256 + (rb >> 3);
  const int bp = vb >> 2;
  const int nt = vb & 3;
  const int tid = threadIdx.x;
  const int w = tid >> 6, l = tid & 63, quad = l >> 4, lm = l & 15;

  // ---- phase 1: S rows (wave w -> row-tile w) x all 256 cols, hi/lo 3-term ----
  f4 sacc[16];
  #pragma unroll
  for (int ct = 0; ct < 16; ++ct) sacc[ct] = (f4)0.f;

  for (int dc = 0; dc < 4; ++dc){
    __syncthreads();
    { // pure copy staging from pre-split chunked planes (coalesced, conflict-free)
      const u16* srch = mh + ((bp*4 + dc) << 13);
      const u16* srcl = ml + ((bp*4 + dc) << 13);
      int m0 = tid >> 2, seg = (tid & 3)*8;
      #pragma unroll
      for (int r = 0; r < 4; ++r){
        int m = m0 + r*64;
        *(uint4*)&mbh[m][seg] = *(const uint4*)&srch[m*32 + seg];
        *(uint4*)&mbl[m][seg] = *(const uint4*)&srcl[m*32 + seg];
      }
    }
    __syncthreads();
    s16x8 amh = *(s16x8*)&mbh[nt*64 + w*16 + lm][quad*8];
    s16x8 aml = *(s16x8*)&mbl[nt*64 + w*16 + lm][quad*8];
    #pragma unroll
    for (int ct = 0; ct < 16; ++ct){
      s16x8 bmh = *(s16x8*)&mbh[ct*16 + lm][quad*8];
      s16x8 bml = *(s16x8*)&mbl[ct*16 + lm][quad*8];
      sacc[ct] = __builtin_amdgcn_mfma_f32_16x16x32_bf16(amh, bmh, sacc[ct], 0, 0, 0);
      sacc[ct] = __builtin_amdgcn_mfma_f32_16x16x32_bf16(amh, bml, sacc[ct], 0, 0, 0);
      sacc[ct] = __builtin_amdgcn_mfma_f32_16x16x32_bf16(aml, bmh, sacc[ct], 0, 0, 0);
    }
  }
  __syncthreads();   // all mbuf reads done; Ps may now overlay

  // ---- softmax (regs only) -> Ps[row][m] bf16 ----
  #pragma unroll
  for (int r = 0; r < 4; ++r){
    int rowg = nt*64 + w*16 + quad*4 + r;
    float v[16]; float mx = -3.0e38f;
    #pragma unroll
    for (int ct = 0; ct < 16; ++ct){
      float t = sacc[ct][r];
      if (ct*16 + lm == rowg) t -= 1e8f;
      t = lrelu(t);
      v[ct] = t; mx = fmaxf(mx, t);
    }
    #pragma unroll
    for (int m = 1; m < 16; m <<= 1) mx = fmaxf(mx, __shfl_xor(mx, m));
    float sum = 0.f;
    #pragma unroll
    for (int ct = 0; ct < 16; ++ct){ float e = __expf(v[ct] - mx); v[ct] = e; sum += e; }
    #pragma unroll
    for (int m = 1; m < 16; m <<= 1) sum += __shfl_xor(sum, m);
    float inv = 1.0f / sum;
    #pragma unroll
    for (int ct = 0; ct < 16; ++ct)
      Ps[w*16 + quad*4 + r][ct*16 + lm] = f2b(v[ct] * inv);
  }

  // ---- phase 2: agg = P @ spa (+ spa for +I). 64-m chunks, conflict-free transpose stage. ----
  f4 acc2[2][4];
  #pragma unroll
  for (int i = 0; i < 2; ++i)
    #pragma unroll
    for (int rt = 0; rt < 4; ++rt) acc2[i][rt] = (f4)0.f;

  for (int mc2 = 0; mc2 < 4; ++mc2){
    __syncthreads();
    { // transpose-stage spa[64 m][128 d] -> spasT[128][72]
      // lanes span full m (mlo = l, all 32 banks via mlo>>1); d0 wave-uniform
      int mlo = tid & 63;
      int db = (tid >> 6)*8;
      const u16* ps = spa + (bp*256 + mc2*64 + mlo)*128;
      #pragma unroll
      for (int r = 0; r < 4; ++r){
        int d0 = db + r*32;
        uint4 v = *(const uint4*)(ps + d0);
        u16 h[8]; *(uint4*)&h[0] = v;
        #pragma unroll
        for (int j = 0; j < 8; ++j) spasT[d0+j][mlo] = h[j];
      }
    }
    __syncthreads();
    #pragma unroll
    for (int ks = 0; ks < 2; ++ks){
      int m0 = ks*32 + quad*8;
      s16x8 afs[2], bfp[4];
      #pragma unroll
      for (int i = 0; i < 2; ++i) afs[i] = *(s16x8*)&spasT[(2*w+i)*16 + lm][m0];
      #pragma unroll
      for (int rt = 0; rt < 4; ++rt) bfp[rt] = *(s16x8*)&Ps[rt*16 + lm][mc2*64 + m0];
      #pragma unroll
      for (int i = 0; i < 2; ++i)
        #pragma unroll
        for (int rt = 0; rt < 4; ++rt)
          acc2[i][rt] = __builtin_amdgcn_mfma_f32_16x16x32_bf16(afs[i], bfp[rt], acc2[i][rt], 0, 0, 0);
    }
  }
  // store: D row=d(quad*4+reg), col=row(lm)
  #pragma unroll
  for (int i = 0; i < 2; ++i){
    int d0 = (2*w+i)*16 + quad*4;
    #pragma unroll
    for (int rt = 0; rt < 4; ++rt){
      int grow = bp*256 + nt*64 + rt*16 + lm;
      uint2 sp = *(const uint2*)&spa[grow*128 + d0];
      f4 a = acc2[i][rt];
      a.x += b2f((u16)(sp.x & 0xffff)); a.y += b2f((u16)(sp.x >> 16));
      a.z += b2f((u16)(sp.y & 0xffff)); a.w += b2f((u16)(sp.y >> 16));
      uint2 p; p.x = pk(a.x, a.y); p.y = pk(a.z, a.w);
      *(uint2*)&agg[grow*128 + d0] = p;
    }
  }
}

// ---------------- final BN + leaky, in place ----------------
__global__ void k_bnout(float* __restrict__ outp){
  int idx = blockIdx.x*256 + threadIdx.x;
  int flat = idx*4;
  int o = flat & 127;
  float4 v = *(const float4*)(outp + flat);
  v.x = lrelu(fmaf(v.x, g_sb[2][0][o+0], g_sb[2][1][o+0]));
  v.y = lrelu(fmaf(v.y, g_sb[2][0][o+1], g_sb[2][1][o+1]));
  v.z = lrelu(fmaf(v.z, g_sb[2][0][o+2], g_sb[2][1][o+2]));
  v.w = lrelu(fmaf(v.w, g_sb[2][0][o+3], g_sb[2][1][o+3]));
  *(float4*)(outp + flat) = v;
}

extern "C" void kernel_launch(void* const* d_in, const int* in_sizes, int n_in,
                              void* d_out, int out_size, void* d_ws, size_t ws_size,
                              hipStream_t stream) {
  const float* x    = (const float*)d_in[0];
  const float* w1   = (const float*)d_in[1];
  const float* bn1g = (const float*)d_in[2];
  const float* bn1b = (const float*)d_in[3];
  const float* w2   = (const float*)d_in[4];
  const float* bn2g = (const float*)d_in[5];
  const float* bn2b = (const float*)d_in[6];
  const float* mapw = (const float*)d_in[7];
  const float* mapb = (const float*)d_in[8];
  const float* thw  = (const float*)d_in[9];
  const float* thb  = (const float*)d_in[10];
  const float* bnSg = (const float*)d_in[11];
  const float* bnSb = (const float*)d_in[12];
  float* outp = (float*)d_out;

  // ws (64 MB): spa (16M bf16) + agg (16M bf16)
  u16* spa = (u16*)d_ws;
  u16* agg = spa + 16777216;

  // d_out scratch phases: y1hl (64 MB) -> mapped hi/lo planes (mh 32MB + ml 32MB) -> out fp32
  u16* y1hl = (u16*)d_out;
  u16* mh   = (u16*)d_out;
  u16* ml   = mh + 16777216;

  k_zero<<<3, 256, 0, stream>>>();
  k_prepw<<<416, 256, 0, stream>>>(w1, w2, mapw, thw);
  k_conv1<<<2048, 256, 0, stream>>>(x, y1hl);
  k_reduce<<<16, 256, 0, stream>>>(0);
  k_finalize<<<1, 128, 0, stream>>>(bn1g, bn1b, 0);
  k_conv2<<<2048, 256, 0, stream>>>(y1hl, spa);
  k_reduce<<<16, 256, 0, stream>>>(1);
  k_finalize<<<1, 128, 0, stream>>>(bn2g, bn2b, 1);
  k_act<<<8192, 256, 0, stream>>>(spa);
  k_gemm128b<<<2048, 256, 0, stream>>>(spa, mapb, (void*)mh, 0, 0);
  k_adjagg<<<2048, 256, 0, stream>>>(mh, ml, spa, agg);
  k_gemm128b<<<2048, 256, 0, stream>>>(agg, thb, (void*)outp, 1, 1);
  k_reduce<<<16, 256, 0, stream>>>(2);
  k_finalize<<<1, 128, 0, stream>>>(bnSg, bnSb, 2);
  k_bnout<<<16384, 256, 0, stream>>>(outp);
}

// Round 3
// 406.925 us; speedup vs baseline: 1.1120x; 1.0555x over previous
//
#include <hip/hip_runtime.h>

#define SLOPE 0.01f
#define EPSB 1e-5f
#define INV_CNT (1.0f/131072.0f)

typedef unsigned short u16;
typedef unsigned int u32;
typedef __attribute__((ext_vector_type(8))) short s16x8;
typedef __attribute__((ext_vector_type(4))) float f4;

__device__ float g_stats[3][2][128];   // [which][sum|sq][channel]
__device__ float g_sb[3][2][128];      // [which][scale|bias][channel]
__device__ float g_part[2048][256];    // per-block partial stats [block][sum128|sq128]
__device__ u16 g_w1h[3][128][64];      // [k][co][ci] hi
__device__ u16 g_w1l[3][128][64];      // lo
__device__ u16 g_w2h[3][128][128];
__device__ u16 g_w2l[3][128][128];
__device__ u16 g_wmh[128][128];        // [e][d]
__device__ u16 g_wml[128][128];
__device__ u16 g_wqh[128][128];        // theta
__device__ u16 g_wql[128][128];

__device__ __forceinline__ float lrelu(float x){ return x > 0.f ? x : SLOPE*x; }
__device__ __forceinline__ u16 f2b(float f){
  u32 u = __float_as_uint(f);
  return (u16)((u + 0x7fffu + ((u >> 16) & 1u)) >> 16);   // RNE
}
__device__ __forceinline__ float b2f(u16 h){ return __uint_as_float(((u32)h) << 16); }
__device__ __forceinline__ u32 pk(float a, float b){ return (u32)f2b(a) | ((u32)f2b(b) << 16); }
__device__ __forceinline__ u32 pkhl(float f){
  u16 h = f2b(f);
  u16 l = f2b(f - b2f(h));
  return (u32)h | ((u32)l << 16);
}
__device__ __forceinline__ float unhl(u32 v){ return b2f((u16)(v & 0xffff)) + b2f((u16)(v >> 16)); }

// ---------------- zero stats ----------------
__global__ void k_zero(){
  int i = blockIdx.x*256 + threadIdx.x;
  if (i < 768) ((float*)g_stats)[i] = 0.f;
}

// ---------------- reduce per-block partials -> g_stats[which] ----------------
__global__ void k_reduce(int which){
  const float* base = &g_part[blockIdx.x*128][0];
  int j = threadIdx.x;
  float s = 0.f;
  #pragma unroll 4
  for (int r = 0; r < 128; ++r) s += base[r*256 + j];
  atomicAdd(&((float*)g_stats)[which*256 + j], s);
}

// ---------------- prep: fp32 weights -> bf16 hi/lo device globals ----------------
__global__ void k_prepw(const float* __restrict__ w1, const float* __restrict__ w2,
                        const float* __restrict__ mapw, const float* __restrict__ thw){
  int idx = blockIdx.x*256 + threadIdx.x;
  if (idx < 24576){
    int kk = idx >> 13, r = idx & 8191, co = r >> 6, ci = r & 63;
    float v = w1[co*192 + ci*3 + kk];
    u16 h = f2b(v);
    g_w1h[kk][co][ci] = h; g_w1l[kk][co][ci] = f2b(v - b2f(h));
  } else if (idx < 73728){
    int j = idx - 24576;
    int kk = j >> 14, r = j & 16383, co = r >> 7, ci = r & 127;
    float v = w2[co*384 + ci*3 + kk];
    u16 h = f2b(v);
    g_w2h[kk][co][ci] = h; g_w2l[kk][co][ci] = f2b(v - b2f(h));
  } else if (idx < 90112){
    int j = idx - 73728;
    float v = mapw[j];
    u16 h = f2b(v);
    ((u16*)g_wmh)[j] = h; ((u16*)g_wml)[j] = f2b(v - b2f(h));
  } else if (idx < 106496){
    int j = idx - 90112;
    float v = thw[j];
    u16 h = f2b(v);
    ((u16*)g_wqh)[j] = h; ((u16*)g_wql)[j] = f2b(v - b2f(h));
  }
}

// ---------------- finalize BN stats -> scale/bias ----------------
__global__ void k_finalize(const float* __restrict__ g, const float* __restrict__ bta, int which){
  int c = threadIdx.x;   // 128
  float mean = g_stats[which][0][c] * INV_CNT;
  float var  = g_stats[which][1][c] * INV_CNT - mean*mean;
  float sc = g[c] * rsqrtf(var + EPSB);
  g_sb[which][0][c] = sc;
  g_sb[which][1][c] = bta[c] - mean*sc;
}

// ---------------- conv1 MFMA: weights direct-from-L2, 1 barrier ----------------
__global__ __launch_bounds__(256, 4) void k_conv1(const float* __restrict__ x, u16* __restrict__ y1hl){
  __shared__ __align__(16) u16 a0h[2][34][72];
  __shared__ __align__(16) u16 a0l[2][34][72];
  const int bid = blockIdx.x;
  const int bn0 = bid*2;
  const int b = bn0 >> 8, n = bn0 & 255;
  const int tid = threadIdx.x;
  const int w = tid >> 6, l = tid & 63, quad = l >> 4, lm = l & 15;
  f4 acc[2][4];
  #pragma unroll
  for (int i = 0; i < 2; ++i)
    #pragma unroll
    for (int j = 0; j < 4; ++j) acc[i][j] = (f4)0.f;

  { // stage x -> a0h/a0l (hi/lo bf16), transposed to [t][ci]
    int nn = tid >> 7, rem = tid & 127, t = rem >> 2, ci0 = (rem & 3)*16;
    const float* px = x + ((b*32 + t)*256 + n + nn)*64 + ci0;
    u16 hh[16], ll[16];
    #pragma unroll
    for (int j = 0; j < 4; ++j){
      float4 v = *(const float4*)(px + 4*j);
      float vv[4] = {v.x, v.y, v.z, v.w};
      #pragma unroll
      for (int e = 0; e < 4; ++e){
        u16 h = f2b(vv[e]);
        hh[4*j+e] = h; ll[4*j+e] = f2b(vv[e] - b2f(h));
      }
    }
    *(uint4*)&a0h[nn][t+1][ci0]   = *(uint4*)&hh[0];
    *(uint4*)&a0h[nn][t+1][ci0+8] = *(uint4*)&hh[8];
    *(uint4*)&a0l[nn][t+1][ci0]   = *(uint4*)&ll[0];
    *(uint4*)&a0l[nn][t+1][ci0+8] = *(uint4*)&ll[8];
  }
  for (int u = tid; u < 288; u += 256){
    int a = u / 144, rr = u % 144, r = rr / 36, cw = rr % 36;
    u32* base = a ? (u32*)&a0l[r>>1][(r&1)*33][0] : (u32*)&a0h[r>>1][(r&1)*33][0];
    base[cw] = 0u;
  }
  __syncthreads();

  for (int kk = 0; kk < 3; ++kk){
    #pragma unroll
    for (int s = 0; s < 2; ++s){
      int ci0 = s*32 + quad*8;
      s16x8 wh[2], wl[2], bh[4], bl[4];
      #pragma unroll
      for (int i = 0; i < 2; ++i){
        wh[i] = *(const s16x8*)&g_w1h[kk][(2*w+i)*16 + lm][ci0];
        wl[i] = *(const s16x8*)&g_w1l[kk][(2*w+i)*16 + lm][ci0];
      }
      #pragma unroll
      for (int nt = 0; nt < 4; ++nt){
        bh[nt] = *(s16x8*)&a0h[nt>>1][(nt&1)*16 + lm + kk][ci0];
        bl[nt] = *(s16x8*)&a0l[nt>>1][(nt&1)*16 + lm + kk][ci0];
      }
      #pragma unroll
      for (int i = 0; i < 2; ++i)
        #pragma unroll
        for (int nt = 0; nt < 4; ++nt){
          acc[i][nt] = __builtin_amdgcn_mfma_f32_16x16x32_bf16(wh[i], bh[nt], acc[i][nt], 0, 0, 0);
          acc[i][nt] = __builtin_amdgcn_mfma_f32_16x16x32_bf16(wh[i], bl[nt], acc[i][nt], 0, 0, 0);
          acc[i][nt] = __builtin_amdgcn_mfma_f32_16x16x32_bf16(wl[i], bh[nt], acc[i][nt], 0, 0, 0);
        }
    }
  }
  // epilogue: D row=co(quad*4+reg), col=t(lm). Store 4 (hi,lo) pairs = uint4.
  #pragma unroll
  for (int i = 0; i < 2; ++i){
    int co0 = (2*w+i)*16 + quad*4;
    float s0=0,s1=0,s2=0,s3=0,q0=0,q1=0,q2=0,q3=0;
    #pragma unroll
    for (int nt = 0; nt < 4; ++nt){
      f4 a = acc[i][nt];
      int nn = nt >> 1, t = (nt & 1)*16 + lm;
      uint4 p;
      p.x = pkhl(a.x); p.y = pkhl(a.y); p.z = pkhl(a.z); p.w = pkhl(a.w);
      *(uint4*)&y1hl[(((bn0+nn)*32 + t)*128 + co0)*2] = p;
      s0+=a.x; s1+=a.y; s2+=a.z; s3+=a.w;
      q0+=a.x*a.x; q1+=a.y*a.y; q2+=a.z*a.z; q3+=a.w*a.w;
    }
    #pragma unroll
    for (int m = 1; m < 16; m <<= 1){
      s0+=__shfl_xor(s0,m); s1+=__shfl_xor(s1,m); s2+=__shfl_xor(s2,m); s3+=__shfl_xor(s3,m);
      q0+=__shfl_xor(q0,m); q1+=__shfl_xor(q1,m); q2+=__shfl_xor(q2,m); q3+=__shfl_xor(q3,m);
    }
    if (lm == 0){
      f4 sv = {s0,s1,s2,s3}, qv = {q0,q1,q2,q3};
      *(f4*)&g_part[bid][co0]       = sv;
      *(f4*)&g_part[bid][128 + co0] = qv;
    }
  }
}

// ---------------- conv2 MFMA: weights direct-from-L2, 1 barrier ----------------
__global__ __launch_bounds__(256, 4) void k_conv2(const u16* __restrict__ y1hl, u16* __restrict__ spa){
  __shared__ __align__(16) u16 a1s[2][34][136];
  const int bid = blockIdx.x;
  const int bn0 = bid*2;
  const int b = bn0 >> 8, n = bn0 & 255;
  const int tid = threadIdx.x;
  const int w = tid >> 6, l = tid & 63, quad = l >> 4, lm = l & 15;
  f4 acc2[4][2];
  #pragma unroll
  for (int mt = 0; mt < 4; ++mt)
    #pragma unroll
    for (int i = 0; i < 2; ++i) acc2[mt][i] = (f4)0.f;

  { // stage bn1+relu(exact y1) -> a1s
    int nn = tid >> 7, rem = tid & 127, t = rem >> 2, ci0 = (rem & 3)*32;
    const u16* py = y1hl + (((bn0+nn)*32 + t)*128)*2;
    #pragma unroll
    for (int j = 0; j < 4; ++j){
      uint4 va = *(const uint4*)&py[(ci0 + 8*j)*2];
      uint4 vb = *(const uint4*)&py[(ci0 + 8*j + 4)*2];
      u32 vv[8] = {va.x, va.y, va.z, va.w, vb.x, vb.y, vb.z, vb.w};
      u16 oo[8];
      #pragma unroll
      for (int e = 0; e < 8; ++e){
        int ci = ci0 + 8*j + e;
        float f = fmaxf(fmaf(unhl(vv[e]), g_sb[0][0][ci], g_sb[0][1][ci]), 0.f);
        oo[e] = f2b(f);
      }
      *(uint4*)&a1s[nn][t+1][ci0 + 8*j] = *(uint4*)&oo[0];
    }
  }
  for (int u = tid; u < 272; u += 256){
    int r = u/68, cw = u%68;
    ((u32*)&a1s[r>>1][(r&1)*33][0])[cw] = 0u;
  }
  __syncthreads();

  for (int kk = 0; kk < 3; ++kk){
    #pragma unroll
    for (int s = 0; s < 4; ++s){
      int ci0 = s*32 + quad*8;
      s16x8 ax[4], bwh[2], bwl[2];
      #pragma unroll
      for (int i = 0; i < 2; ++i){
        bwh[i] = *(const s16x8*)&g_w2h[kk][(2*w+i)*16 + lm][ci0];
        bwl[i] = *(const s16x8*)&g_w2l[kk][(2*w+i)*16 + lm][ci0];
      }
      #pragma unroll
      for (int mt = 0; mt < 4; ++mt) ax[mt] = *(s16x8*)&a1s[mt>>1][(mt&1)*16 + lm + kk][ci0];
      #pragma unroll
      for (int mt = 0; mt < 4; ++mt)
        #pragma unroll
        for (int i = 0; i < 2; ++i){
          acc2[mt][i] = __builtin_amdgcn_mfma_f32_16x16x32_bf16(ax[mt], bwh[i], acc2[mt][i], 0, 0, 0);
          acc2[mt][i] = __builtin_amdgcn_mfma_f32_16x16x32_bf16(ax[mt], bwl[i], acc2[mt][i], 0, 0, 0);
        }
    }
  }
  // epilogue: D row=t(quad*4+reg), col=co(lm); permuted spa store (pre-BN2), partial stats
  #pragma unroll
  for (int i = 0; i < 2; ++i){
    int co = (2*w+i)*16 + lm;
    float s = 0.f, q = 0.f;
    #pragma unroll
    for (int mt = 0; mt < 4; ++mt){
      f4 a = acc2[mt][i];
      int off0 = co*32 + (mt&1)*16 + quad*4;       // off = co*32 + t
      int tp = off0 >> 7, cp = off0 & 127;
      int row = (b*32 + tp)*256 + (n + (mt>>1));
      uint2 p; p.x = pk(a.x, a.y); p.y = pk(a.z, a.w);
      *(uint2*)&spa[row*128 + cp] = p;
      s += a.x + a.y + a.z + a.w;
      q += a.x*a.x + a.y*a.y + a.z*a.z + a.w*a.w;
    }
    s += __shfl_xor(s, 16); s += __shfl_xor(s, 32);
    q += __shfl_xor(q, 16); q += __shfl_xor(q, 32);
    if (l < 16){
      g_part[bid][co]       = s;
      g_part[bid][128 + co] = q;
    }
  }
}

// ---------------- gemm128 MFMA: weights direct-from-L2, 1 barrier; optional fused BN2+relu on A ----------------
// wsel=0 (map): A=spa pre-BN (apply BN2+relu inline), write hi/lo bf16 planes chunked; wsel=1 (theta): fp32 + stats
__global__ __launch_bounds__(256, 4) void k_gemm128b(const u16* __restrict__ A,
                                                     const float* __restrict__ bvec,
                                                     void* __restrict__ outv,
                                                     int wsel, int do_stats){
  __shared__ __align__(16) u16 As[64][136];
  const u16* Wh = wsel ? &g_wqh[0][0] : &g_wmh[0][0];
  const u16* Wl = wsel ? &g_wql[0][0] : &g_wml[0][0];
  const int bid = blockIdx.x;
  const int rowbase = bid * 64;
  const int tid = threadIdx.x;
  const int w = tid >> 6, l = tid & 63, quad = l >> 4, lm = l & 15;
  f4 acc[2][4];
  #pragma unroll
  for (int i = 0; i < 2; ++i)
    #pragma unroll
    for (int rt = 0; rt < 4; ++rt) acc[i][rt] = (f4)0.f;

  { int r = tid >> 2, c0 = (tid & 3)*32;
    int row = rowbase + r;
    if (wsel == 0){
      // fused BN2+relu: channel = tp*4 + chunk, tp = (row>>8)&31, chunk = tid&3
      int c = ((row >> 8) & 31)*4 + (tid & 3);
      float sc = g_sb[1][0][c], bi = g_sb[1][1][c];
      #pragma unroll
      for (int j = 0; j < 4; ++j){
        uint4 v = *(const uint4*)&A[row*128 + c0 + 8*j];
        u32 vv[4] = {v.x, v.y, v.z, v.w};
        u16 oo[8];
        #pragma unroll
        for (int e = 0; e < 4; ++e){
          oo[2*e]   = f2b(fmaxf(fmaf(b2f((u16)(vv[e] & 0xffff)), sc, bi), 0.f));
          oo[2*e+1] = f2b(fmaxf(fmaf(b2f((u16)(vv[e] >> 16)),    sc, bi), 0.f));
        }
        *(uint4*)&As[r][c0 + 8*j] = *(uint4*)&oo[0];
      }
    } else {
      #pragma unroll
      for (int j = 0; j < 4; ++j)
        *(uint4*)&As[r][c0 + 8*j] = *(const uint4*)&A[row*128 + c0 + 8*j];
    }
  }
  __syncthreads();

  #pragma unroll
  for (int s = 0; s < 4; ++s){
    int k0 = s*32 + quad*8;
    s16x8 awh[2], awl[2], ba[4];
    #pragma unroll
    for (int i = 0; i < 2; ++i){
      awh[i] = *(const s16x8*)&Wh[((2*w+i)*16 + lm)*128 + k0];
      awl[i] = *(const s16x8*)&Wl[((2*w+i)*16 + lm)*128 + k0];
    }
    #pragma unroll
    for (int rt = 0; rt < 4; ++rt) ba[rt] = *(s16x8*)&As[rt*16 + lm][k0];
    #pragma unroll
    for (int i = 0; i < 2; ++i)
      #pragma unroll
      for (int rt = 0; rt < 4; ++rt){
        acc[i][rt] = __builtin_amdgcn_mfma_f32_16x16x32_bf16(awh[i], ba[rt], acc[i][rt], 0, 0, 0);
        acc[i][rt] = __builtin_amdgcn_mfma_f32_16x16x32_bf16(awl[i], ba[rt], acc[i][rt], 0, 0, 0);
      }
  }
  // epilogue: D row=e(quad*4+reg), col=row(lm)
  #pragma unroll
  for (int i = 0; i < 2; ++i){
    int e0 = (2*w+i)*16 + quad*4;
    f4 bv = *(const f4*)&bvec[e0];
    if (wsel == 0){
      // mapped mode: hi/lo planes, chunked [bp][dc][m][32]
      u16* mh = (u16*)outv;
      u16* ml = mh + 16777216;
      int dc = e0 >> 5, ec = e0 & 31;
      #pragma unroll
      for (int rt = 0; rt < 4; ++rt){
        int row = rowbase + rt*16 + lm;
        int bp = row >> 8, m = row & 255;
        f4 o = acc[i][rt] + bv;
        float fv[4] = {o.x, o.y, o.z, o.w};
        u16 hh[4], ll[4];
        #pragma unroll
        for (int e = 0; e < 4; ++e){
          u16 h = f2b(fv[e]);
          hh[e] = h; ll[e] = f2b(fv[e] - b2f(h));
        }
        int off = ((bp*4 + dc)*256 + m)*32 + ec;
        *(uint2*)&mh[off] = *(uint2*)&hh[0];
        *(uint2*)&ml[off] = *(uint2*)&ll[0];
      }
    } else {
      float* outp = (float*)outv;
      f4 sv = (f4)0.f, qv = (f4)0.f;
      #pragma unroll
      for (int rt = 0; rt < 4; ++rt){
        int row = rowbase + rt*16 + lm;
        f4 o = acc[i][rt] + bv;
        *(f4*)&outp[row*128 + e0] = o;
        sv += o; qv += o*o;
      }
      if (do_stats){
        #pragma unroll
        for (int m = 1; m < 16; m <<= 1){
          sv.x+=__shfl_xor(sv.x,m); sv.y+=__shfl_xor(sv.y,m); sv.z+=__shfl_xor(sv.z,m); sv.w+=__shfl_xor(sv.w,m);
          qv.x+=__shfl_xor(qv.x,m); qv.y+=__shfl_xor(qv.y,m); qv.z+=__shfl_xor(qv.z,m); qv.w+=__shfl_xor(qv.w,m);
        }
        if (lm == 0){
          *(f4*)&g_part[bid][e0]       = sv;
          *(f4*)&g_part[bid][128 + e0] = qv;
        }
      }
    }
  }
}

// ---------------- fused adj+agg MFMA; spa consumed pre-BN2 with fused BN2+relu ----------------
__global__ __launch_bounds__(256) void k_adjagg(const u16* __restrict__ mh,
                                                const u16* __restrict__ ml,
                                                const u16* __restrict__ spa,
                                                u16* __restrict__ agg){
  __shared__ __align__(16) char smem[52224];
  u16 (*mbh)[40]   = (u16(*)[40])(smem);
  u16 (*mbl)[40]   = (u16(*)[40])(smem + 20480);
  u16 (*Ps)[264]   = (u16(*)[264])(smem);            // [64][264] = 33792 B
  u16 (*spasT)[72] = (u16(*)[72])(smem + 33792);     // [128][72] = 18432 B
  // XCD-aware remap: 4 nt-blocks of one bp land consecutively on the same XCD
  const int rb = blockIdx.x;
  const int vb = (rb & 7)*256 + (rb >> 3);
  const int bp = vb >> 2;
  const int nt = vb & 3;
  const int tid = threadIdx.x;
  const int w = tid >> 6, l = tid & 63, quad = l >> 4, lm = l & 15;
  const int tp4 = (bp & 31)*4;

  // ---- phase 1: S rows (wave w -> row-tile w) x all 256 cols, hi/lo 3-term ----
  f4 sacc[16];
  #pragma unroll
  for (int ct = 0; ct < 16; ++ct) sacc[ct] = (f4)0.f;

  for (int dc = 0; dc < 4; ++dc){
    __syncthreads();
    { // pure copy staging from pre-split chunked planes (coalesced, conflict-free)
      const u16* srch = mh + ((bp*4 + dc) << 13);
      const u16* srcl = ml + ((bp*4 + dc) << 13);
      int m0 = tid >> 2, seg = (tid & 3)*8;
      #pragma unroll
      for (int r = 0; r < 4; ++r){
        int m = m0 + r*64;
        *(uint4*)&mbh[m][seg] = *(const uint4*)&srch[m*32 + seg];
        *(uint4*)&mbl[m][seg] = *(const uint4*)&srcl[m*32 + seg];
      }
    }
    __syncthreads();
    s16x8 amh = *(s16x8*)&mbh[nt*64 + w*16 + lm][quad*8];
    s16x8 aml = *(s16x8*)&mbl[nt*64 + w*16 + lm][quad*8];
    #pragma unroll
    for (int ct = 0; ct < 16; ++ct){
      s16x8 bmh = *(s16x8*)&mbh[ct*16 + lm][quad*8];
      s16x8 bml = *(s16x8*)&mbl[ct*16 + lm][quad*8];
      sacc[ct] = __builtin_amdgcn_mfma_f32_16x16x32_bf16(amh, bmh, sacc[ct], 0, 0, 0);
      sacc[ct] = __builtin_amdgcn_mfma_f32_16x16x32_bf16(amh, bml, sacc[ct], 0, 0, 0);
      sacc[ct] = __builtin_amdgcn_mfma_f32_16x16x32_bf16(aml, bmh, sacc[ct], 0, 0, 0);
    }
  }
  __syncthreads();   // all mbuf reads done; Ps may now overlay

  // ---- softmax (regs only) -> Ps[row][m] bf16 ----
  #pragma unroll
  for (int r = 0; r < 4; ++r){
    int rowg = nt*64 + w*16 + quad*4 + r;
    float v[16]; float mx = -3.0e38f;
    #pragma unroll
    for (int ct = 0; ct < 16; ++ct){
      float t = sacc[ct][r];
      if (ct*16 + lm == rowg) t -= 1e8f;
      t = lrelu(t);
      v[ct] = t; mx = fmaxf(mx, t);
    }
    #pragma unroll
    for (int m = 1; m < 16; m <<= 1) mx = fmaxf(mx, __shfl_xor(mx, m));
    float sum = 0.f;
    #pragma unroll
    for (int ct = 0; ct < 16; ++ct){ float e = __expf(v[ct] - mx); v[ct] = e; sum += e; }
    #pragma unroll
    for (int m = 1; m < 16; m <<= 1) sum += __shfl_xor(sum, m);
    float inv = 1.0f / sum;
    #pragma unroll
    for (int ct = 0; ct < 16; ++ct)
      Ps[w*16 + quad*4 + r][ct*16 + lm] = f2b(v[ct] * inv);
  }

  // ---- phase 2: agg = P @ act(spa) (+ act(spa) for +I). BN2+relu fused at read. ----
  f4 acc2[2][4];
  #pragma unroll
  for (int i = 0; i < 2; ++i)
    #pragma unroll
    for (int rt = 0; rt < 4; ++rt) acc2[i][rt] = (f4)0.f;

  for (int mc2 = 0; mc2 < 4; ++mc2){
    __syncthreads();
    { // transpose-stage act(spa)[64 m][128 d] -> spasT[128][72]
      int mlo = tid & 63;
      int db = (tid >> 6)*8;
      const u16* ps = spa + (bp*256 + mc2*64 + mlo)*128;
      #pragma unroll
      for (int r = 0; r < 4; ++r){
        int d0 = db + r*32;
        float sc = g_sb[1][0][tp4 + r], bi = g_sb[1][1][tp4 + r];   // d0>>5 == r
        uint4 v = *(const uint4*)(ps + d0);
        u16 h[8]; *(uint4*)&h[0] = v;
        #pragma unroll
        for (int j = 0; j < 8; ++j)
          spasT[d0+j][mlo] = f2b(fmaxf(fmaf(b2f(h[j]), sc, bi), 0.f));
      }
    }
    __syncthreads();
    #pragma unroll
    for (int ks = 0; ks < 2; ++ks){
      int m0 = ks*32 + quad*8;
      s16x8 afs[2], bfp[4];
      #pragma unroll
      for (int i = 0; i < 2; ++i) afs[i] = *(s16x8*)&spasT[(2*w+i)*16 + lm][m0];
      #pragma unroll
      for (int rt = 0; rt < 4; ++rt) bfp[rt] = *(s16x8*)&Ps[rt*16 + lm][mc2*64 + m0];
      #pragma unroll
      for (int i = 0; i < 2; ++i)
        #pragma unroll
        for (int rt = 0; rt < 4; ++rt)
          acc2[i][rt] = __builtin_amdgcn_mfma_f32_16x16x32_bf16(afs[i], bfp[rt], acc2[i][rt], 0, 0, 0);
    }
  }
  // store: D row=d(quad*4+reg), col=row(lm); +I term with fused BN2+relu (bit-identical roundtrip)
  #pragma unroll
  for (int i = 0; i < 2; ++i){
    int d0 = (2*w+i)*16 + quad*4;
    int c = tp4 + (d0 >> 5);
    float sc = g_sb[1][0][c], bi = g_sb[1][1][c];
    #pragma unroll
    for (int rt = 0; rt < 4; ++rt){
      int grow = bp*256 + nt*64 + rt*16 + lm;
      uint2 sp = *(const uint2*)&spa[grow*128 + d0];
      f4 a = acc2[i][rt];
      a.x += b2f(f2b(fmaxf(fmaf(b2f((u16)(sp.x & 0xffff)), sc, bi), 0.f)));
      a.y += b2f(f2b(fmaxf(fmaf(b2f((u16)(sp.x >> 16)),    sc, bi), 0.f)));
      a.z += b2f(f2b(fmaxf(fmaf(b2f((u16)(sp.y & 0xffff)), sc, bi), 0.f)));
      a.w += b2f(f2b(fmaxf(fmaf(b2f((u16)(sp.y >> 16)),    sc, bi), 0.f)));
      uint2 p; p.x = pk(a.x, a.y); p.y = pk(a.z, a.w);
      *(uint2*)&agg[grow*128 + d0] = p;
    }
  }
}

// ---------------- final BN + leaky, in place ----------------
__global__ void k_bnout(float* __restrict__ outp){
  int idx = blockIdx.x*256 + threadIdx.x;
  int flat = idx*4;
  int o = flat & 127;
  float4 v = *(const float4*)(outp + flat);
  v.x = lrelu(fmaf(v.x, g_sb[2][0][o+0], g_sb[2][1][o+0]));
  v.y = lrelu(fmaf(v.y, g_sb[2][0][o+1], g_sb[2][1][o+1]));
  v.z = lrelu(fmaf(v.z, g_sb[2][0][o+2], g_sb[2][1][o+2]));
  v.w = lrelu(fmaf(v.w, g_sb[2][0][o+3], g_sb[2][1][o+3]));
  *(float4*)(outp + flat) = v;
}

extern "C" void kernel_launch(void* const* d_in, const int* in_sizes, int n_in,
                              void* d_out, int out_size, void* d_ws, size_t ws_size,
                              hipStream_t stream) {
  const float* x    = (const float*)d_in[0];
  const float* w1   = (const float*)d_in[1];
  const float* bn1g = (const float*)d_in[2];
  const float* bn1b = (const float*)d_in[3];
  const float* w2   = (const float*)d_in[4];
  const float* bn2g = (const float*)d_in[5];
  const float* bn2b = (const float*)d_in[6];
  const float* mapw = (const float*)d_in[7];
  const float* mapb = (const float*)d_in[8];
  const float* thw  = (const float*)d_in[9];
  const float* thb  = (const float*)d_in[10];
  const float* bnSg = (const float*)d_in[11];
  const float* bnSb = (const float*)d_in[12];
  float* outp = (float*)d_out;

  // ws (64 MB): spa (16M bf16, PRE-BN2) + agg (16M bf16)
  u16* spa = (u16*)d_ws;
  u16* agg = spa + 16777216;

  // d_out scratch phases: y1hl (64 MB) -> mapped hi/lo planes (mh 32MB + ml 32MB) -> out fp32
  u16* y1hl = (u16*)d_out;
  u16* mh   = (u16*)d_out;
  u16* ml   = mh + 16777216;

  k_zero<<<3, 256, 0, stream>>>();
  k_prepw<<<416, 256, 0, stream>>>(w1, w2, mapw, thw);
  k_conv1<<<2048, 256, 0, stream>>>(x, y1hl);
  k_reduce<<<16, 256, 0, stream>>>(0);
  k_finalize<<<1, 128, 0, stream>>>(bn1g, bn1b, 0);
  k_conv2<<<2048, 256, 0, stream>>>(y1hl, spa);
  k_reduce<<<16, 256, 0, stream>>>(1);
  k_finalize<<<1, 128, 0, stream>>>(bn2g, bn2b, 1);
  k_gemm128b<<<2048, 256, 0, stream>>>(spa, mapb, (void*)mh, 0, 0);
  k_adjagg<<<2048, 256, 0, stream>>>(mh, ml, spa, agg);
  k_gemm128b<<<2048, 256, 0, stream>>>(agg, thb, (void*)outp, 1, 1);
  k_reduce<<<16, 256, 0, stream>>>(2);
  k_finalize<<<1, 128, 0, stream>>>(bnSg, bnSb, 2);
  k_bnout<<<16384, 256, 0, stream>>>(outp);
}

// Round 5
// 406.221 us; speedup vs baseline: 1.1139x; 1.0017x over previous
//
#include <hip/hip_runtime.h>

#define SLOPE 0.01f
#define EPSB 1e-5f
#define INV_CNT (1.0f/131072.0f)

typedef unsigned short u16;
typedef unsigned int u32;
typedef __attribute__((ext_vector_type(8))) short s16x8;
typedef __attribute__((ext_vector_type(4))) float f4;

__device__ float g_stats[3][2][128];   // [which][sum|sq][channel]
__device__ float g_sb[3][2][128];      // [which][scale|bias][channel]
__device__ float g_part[2048][256];    // per-block partial stats [block][sum128|sq128]
__device__ u16 g_w1h[3][128][64];      // [k][co][ci] hi
__device__ u16 g_w1l[3][128][64];      // lo
__device__ u16 g_w2h[3][128][128];
__device__ u16 g_w2l[3][128][128];
__device__ u16 g_wmh[128][128];        // [e][d]
__device__ u16 g_wml[128][128];
__device__ u16 g_wqh[128][128];        // theta
__device__ u16 g_wql[128][128];

__device__ __forceinline__ float lrelu(float x){ return x > 0.f ? x : SLOPE*x; }
__device__ __forceinline__ u16 f2b(float f){
  u32 u = __float_as_uint(f);
  return (u16)((u + 0x7fffu + ((u >> 16) & 1u)) >> 16);   // RNE
}
__device__ __forceinline__ float b2f(u16 h){ return __uint_as_float(((u32)h) << 16); }
__device__ __forceinline__ u32 pk(float a, float b){ return (u32)f2b(a) | ((u32)f2b(b) << 16); }
__device__ __forceinline__ u32 pkhl(float f){
  u16 h = f2b(f);
  u16 l = f2b(f - b2f(h));
  return (u32)h | ((u32)l << 16);
}
__device__ __forceinline__ float unhl(u32 v){ return b2f((u16)(v & 0xffff)) + b2f((u16)(v >> 16)); }

// ---------------- zero stats ----------------
__global__ void k_zero(){
  int i = blockIdx.x*256 + threadIdx.x;
  if (i < 768) ((float*)g_stats)[i] = 0.f;
}

// ---------------- reduce per-block partials -> g_stats[which] ----------------
__global__ void k_reduce(int which){
  const float* base = &g_part[blockIdx.x*128][0];
  int j = threadIdx.x;
  float s = 0.f;
  #pragma unroll 4
  for (int r = 0; r < 128; ++r) s += base[r*256 + j];
  atomicAdd(&((float*)g_stats)[which*256 + j], s);
}

// ---------------- prep: fp32 weights -> bf16 hi/lo device globals ----------------
__global__ void k_prepw(const float* __restrict__ w1, const float* __restrict__ w2,
                        const float* __restrict__ mapw, const float* __restrict__ thw){
  int idx = blockIdx.x*256 + threadIdx.x;
  if (idx < 24576){
    int kk = idx >> 13, r = idx & 8191, co = r >> 6, ci = r & 63;
    float v = w1[co*192 + ci*3 + kk];
    u16 h = f2b(v);
    g_w1h[kk][co][ci] = h; g_w1l[kk][co][ci] = f2b(v - b2f(h));
  } else if (idx < 73728){
    int j = idx - 24576;
    int kk = j >> 14, r = j & 16383, co = r >> 7, ci = r & 127;
    float v = w2[co*384 + ci*3 + kk];
    u16 h = f2b(v);
    g_w2h[kk][co][ci] = h; g_w2l[kk][co][ci] = f2b(v - b2f(h));
  } else if (idx < 90112){
    int j = idx - 73728;
    float v = mapw[j];
    u16 h = f2b(v);
    ((u16*)g_wmh)[j] = h; ((u16*)g_wml)[j] = f2b(v - b2f(h));
  } else if (idx < 106496){
    int j = idx - 90112;
    float v = thw[j];
    u16 h = f2b(v);
    ((u16*)g_wqh)[j] = h; ((u16*)g_wql)[j] = f2b(v - b2f(h));
  }
}

// ---------------- finalize BN stats -> scale/bias ----------------
__global__ void k_finalize(const float* __restrict__ g, const float* __restrict__ bta, int which){
  int c = threadIdx.x;   // 128
  float mean = g_stats[which][0][c] * INV_CNT;
  float var  = g_stats[which][1][c] * INV_CNT - mean*mean;
  float sc = g[c] * rsqrtf(var + EPSB);
  g_sb[which][0][c] = sc;
  g_sb[which][1][c] = bta[c] - mean*sc;
}

// ---------------- conv1 MFMA: weights direct-from-L2, 1 barrier ----------------
__global__ __launch_bounds__(256, 4) void k_conv1(const float* __restrict__ x, u16* __restrict__ y1hl){
  __shared__ __align__(16) u16 a0h[2][34][72];
  __shared__ __align__(16) u16 a0l[2][34][72];
  const int bid = blockIdx.x;
  const int bn0 = bid*2;
  const int b = bn0 >> 8, n = bn0 & 255;
  const int tid = threadIdx.x;
  const int w = tid >> 6, l = tid & 63, quad = l >> 4, lm = l & 15;
  f4 acc[2][4];
  #pragma unroll
  for (int i = 0; i < 2; ++i)
    #pragma unroll
    for (int j = 0; j < 4; ++j) acc[i][j] = (f4)0.f;

  { // stage x -> a0h/a0l (hi/lo bf16), transposed to [t][ci]
    int nn = tid >> 7, rem = tid & 127, t = rem >> 2, ci0 = (rem & 3)*16;
    const float* px = x + ((b*32 + t)*256 + n + nn)*64 + ci0;
    u16 hh[16], ll[16];
    #pragma unroll
    for (int j = 0; j < 4; ++j){
      float4 v = *(const float4*)(px + 4*j);
      float vv[4] = {v.x, v.y, v.z, v.w};
      #pragma unroll
      for (int e = 0; e < 4; ++e){
        u16 h = f2b(vv[e]);
        hh[4*j+e] = h; ll[4*j+e] = f2b(vv[e] - b2f(h));
      }
    }
    *(uint4*)&a0h[nn][t+1][ci0]   = *(uint4*)&hh[0];
    *(uint4*)&a0h[nn][t+1][ci0+8] = *(uint4*)&hh[8];
    *(uint4*)&a0l[nn][t+1][ci0]   = *(uint4*)&ll[0];
    *(uint4*)&a0l[nn][t+1][ci0+8] = *(uint4*)&ll[8];
  }
  for (int u = tid; u < 288; u += 256){
    int a = u / 144, rr = u % 144, r = rr / 36, cw = rr % 36;
    u32* base = a ? (u32*)&a0l[r>>1][(r&1)*33][0] : (u32*)&a0h[r>>1][(r&1)*33][0];
    base[cw] = 0u;
  }
  __syncthreads();

  for (int kk = 0; kk < 3; ++kk){
    #pragma unroll
    for (int s = 0; s < 2; ++s){
      int ci0 = s*32 + quad*8;
      s16x8 wh[2], wl[2], bh[4], bl[4];
      #pragma unroll
      for (int i = 0; i < 2; ++i){
        wh[i] = *(const s16x8*)&g_w1h[kk][(2*w+i)*16 + lm][ci0];
        wl[i] = *(const s16x8*)&g_w1l[kk][(2*w+i)*16 + lm][ci0];
      }
      #pragma unroll
      for (int nt = 0; nt < 4; ++nt){
        bh[nt] = *(s16x8*)&a0h[nt>>1][(nt&1)*16 + lm + kk][ci0];
        bl[nt] = *(s16x8*)&a0l[nt>>1][(nt&1)*16 + lm + kk][ci0];
      }
      #pragma unroll
      for (int i = 0; i < 2; ++i)
        #pragma unroll
        for (int nt = 0; nt < 4; ++nt){
          acc[i][nt] = __builtin_amdgcn_mfma_f32_16x16x32_bf16(wh[i], bh[nt], acc[i][nt], 0, 0, 0);
          acc[i][nt] = __builtin_amdgcn_mfma_f32_16x16x32_bf16(wh[i], bl[nt], acc[i][nt], 0, 0, 0);
          acc[i][nt] = __builtin_amdgcn_mfma_f32_16x16x32_bf16(wl[i], bh[nt], acc[i][nt], 0, 0, 0);
        }
    }
  }
  // epilogue: D row=co(quad*4+reg), col=t(lm). Store 4 (hi,lo) pairs = uint4.
  #pragma unroll
  for (int i = 0; i < 2; ++i){
    int co0 = (2*w+i)*16 + quad*4;
    float s0=0,s1=0,s2=0,s3=0,q0=0,q1=0,q2=0,q3=0;
    #pragma unroll
    for (int nt = 0; nt < 4; ++nt){
      f4 a = acc[i][nt];
      int nn = nt >> 1, t = (nt & 1)*16 + lm;
      uint4 p;
      p.x = pkhl(a.x); p.y = pkhl(a.y); p.z = pkhl(a.z); p.w = pkhl(a.w);
      *(uint4*)&y1hl[(((bn0+nn)*32 + t)*128 + co0)*2] = p;
      s0+=a.x; s1+=a.y; s2+=a.z; s3+=a.w;
      q0+=a.x*a.x; q1+=a.y*a.y; q2+=a.z*a.z; q3+=a.w*a.w;
    }
    #pragma unroll
    for (int m = 1; m < 16; m <<= 1){
      s0+=__shfl_xor(s0,m); s1+=__shfl_xor(s1,m); s2+=__shfl_xor(s2,m); s3+=__shfl_xor(s3,m);
      q0+=__shfl_xor(q0,m); q1+=__shfl_xor(q1,m); q2+=__shfl_xor(q2,m); q3+=__shfl_xor(q3,m);
    }
    if (lm == 0){
      f4 sv = {s0,s1,s2,s3}, qv = {q0,q1,q2,q3};
      *(f4*)&g_part[bid][co0]       = sv;
      *(f4*)&g_part[bid][128 + co0] = qv;
    }
  }
}

// ---------------- conv2 MFMA: weights direct-from-L2, 1 barrier ----------------
__global__ __launch_bounds__(256, 4) void k_conv2(const u16* __restrict__ y1hl, u16* __restrict__ spa){
  __shared__ __align__(16) u16 a1s[2][34][136];
  const int bid = blockIdx.x;
  const int bn0 = bid*2;
  const int b = bn0 >> 8, n = bn0 & 255;
  const int tid = threadIdx.x;
  const int w = tid >> 6, l = tid & 63, quad = l >> 4, lm = l & 15;
  f4 acc2[4][2];
  #pragma unroll
  for (int mt = 0; mt < 4; ++mt)
    #pragma unroll
    for (int i = 0; i < 2; ++i) acc2[mt][i] = (f4)0.f;

  { // stage bn1+relu(exact y1) -> a1s
    int nn = tid >> 7, rem = tid & 127, t = rem >> 2, ci0 = (rem & 3)*32;
    const u16* py = y1hl + (((bn0+nn)*32 + t)*128)*2;
    #pragma unroll
    for (int j = 0; j < 4; ++j){
      uint4 va = *(const uint4*)&py[(ci0 + 8*j)*2];
      uint4 vb = *(const uint4*)&py[(ci0 + 8*j + 4)*2];
      u32 vv[8] = {va.x, va.y, va.z, va.w, vb.x, vb.y, vb.z, vb.w};
      u16 oo[8];
      #pragma unroll
      for (int e = 0; e < 8; ++e){
        int ci = ci0 + 8*j + e;
        float f = fmaxf(fmaf(unhl(vv[e]), g_sb[0][0][ci], g_sb[0][1][ci]), 0.f);
        oo[e] = f2b(f);
      }
      *(uint4*)&a1s[nn][t+1][ci0 + 8*j] = *(uint4*)&oo[0];
    }
  }
  for (int u = tid; u < 272; u += 256){
    int r = u/68, cw = u%68;
    ((u32*)&a1s[r>>1][(r&1)*33][0])[cw] = 0u;
  }
  __syncthreads();

  for (int kk = 0; kk < 3; ++kk){
    #pragma unroll
    for (int s = 0; s < 4; ++s){
      int ci0 = s*32 + quad*8;
      s16x8 ax[4], bwh[2], bwl[2];
      #pragma unroll
      for (int i = 0; i < 2; ++i){
        bwh[i] = *(const s16x8*)&g_w2h[kk][(2*w+i)*16 + lm][ci0];
        bwl[i] = *(const s16x8*)&g_w2l[kk][(2*w+i)*16 + lm][ci0];
      }
      #pragma unroll
      for (int mt = 0; mt < 4; ++mt) ax[mt] = *(s16x8*)&a1s[mt>>1][(mt&1)*16 + lm + kk][ci0];
      #pragma unroll
      for (int mt = 0; mt < 4; ++mt)
        #pragma unroll
        for (int i = 0; i < 2; ++i){
          acc2[mt][i] = __builtin_amdgcn_mfma_f32_16x16x32_bf16(ax[mt], bwh[i], acc2[mt][i], 0, 0, 0);
          acc2[mt][i] = __builtin_amdgcn_mfma_f32_16x16x32_bf16(ax[mt], bwl[i], acc2[mt][i], 0, 0, 0);
        }
    }
  }
  // epilogue: D row=t(quad*4+reg), col=co(lm); permuted spa store (pre-BN2), partial stats
  #pragma unroll
  for (int i = 0; i < 2; ++i){
    int co = (2*w+i)*16 + lm;
    float s = 0.f, q = 0.f;
    #pragma unroll
    for (int mt = 0; mt < 4; ++mt){
      f4 a = acc2[mt][i];
      int off0 = co*32 + (mt&1)*16 + quad*4;       // off = co*32 + t
      int tp = off0 >> 7, cp = off0 & 127;
      int row = (b*32 + tp)*256 + (n + (mt>>1));
      uint2 p; p.x = pk(a.x, a.y); p.y = pk(a.z, a.w);
      *(uint2*)&spa[row*128 + cp] = p;
      s += a.x + a.y + a.z + a.w;
      q += a.x*a.x + a.y*a.y + a.z*a.z + a.w*a.w;
    }
    s += __shfl_xor(s, 16); s += __shfl_xor(s, 32);
    q += __shfl_xor(q, 16); q += __shfl_xor(q, 32);
    if (l < 16){
      g_part[bid][co]       = s;
      g_part[bid][128 + co] = q;
    }
  }
}

// ---------------- gemm128 MFMA: weights direct-from-L2, 1 barrier ----------------
// wsel=0 (map): A=spa pre-BN -> apply BN2+relu inline, write activated rows back via spaw
//               (separate NON-restrict pointer, same buffer), write hi/lo planes chunked.
// wsel=1 (theta): fp32 out + stats. spaw unused.
__global__ __launch_bounds__(256, 4) void k_gemm128b(const u16* A,
                                                     u16* spaw,
                                                     const float* __restrict__ bvec,
                                                     void* __restrict__ outv,
                                                     int wsel, int do_stats){
  __shared__ __align__(16) u16 As[64][136];
  const u16* Wh = wsel ? &g_wqh[0][0] : &g_wmh[0][0];
  const u16* Wl = wsel ? &g_wql[0][0] : &g_wml[0][0];
  const int bid = blockIdx.x;
  const int rowbase = bid * 64;
  const int tid = threadIdx.x;
  const int w = tid >> 6, l = tid & 63, quad = l >> 4, lm = l & 15;
  f4 acc[2][4];
  #pragma unroll
  for (int i = 0; i < 2; ++i)
    #pragma unroll
    for (int rt = 0; rt < 4; ++rt) acc[i][rt] = (f4)0.f;

  { int r = tid >> 2, c0 = (tid & 3)*32;
    int row = rowbase + r;
    if (wsel == 0){
      // fused BN2+relu: channel = tp*4 + chunk, tp = (row>>8)&31, chunk = tid&3
      int c = ((row >> 8) & 31)*4 + (tid & 3);
      float sc = g_sb[1][0][c], bi = g_sb[1][1][c];
      #pragma unroll
      for (int j = 0; j < 4; ++j){
        uint4 v = *(const uint4*)&A[row*128 + c0 + 8*j];
        u32 vv[4] = {v.x, v.y, v.z, v.w};
        u16 oo[8];
        #pragma unroll
        for (int e = 0; e < 4; ++e){
          oo[2*e]   = f2b(fmaxf(fmaf(b2f((u16)(vv[e] & 0xffff)), sc, bi), 0.f));
          oo[2*e+1] = f2b(fmaxf(fmaf(b2f((u16)(vv[e] >> 16)),    sc, bi), 0.f));
        }
        uint4 ov = *(uint4*)&oo[0];
        *(uint4*)&As[r][c0 + 8*j] = ov;
        *(uint4*)&spaw[row*128 + c0 + 8*j] = ov;   // activated write-back
      }
    } else {
      #pragma unroll
      for (int j = 0; j < 4; ++j)
        *(uint4*)&As[r][c0 + 8*j] = *(const uint4*)&A[row*128 + c0 + 8*j];
    }
  }
  __syncthreads();

  #pragma unroll
  for (int s = 0; s < 4; ++s){
    int k0 = s*32 + quad*8;
    s16x8 awh[2], awl[2], ba[4];
    #pragma unroll
    for (int i = 0; i < 2; ++i){
      awh[i] = *(const s16x8*)&Wh[((2*w+i)*16 + lm)*128 + k0];
      awl[i] = *(const s16x8*)&Wl[((2*w+i)*16 + lm)*128 + k0];
    }
    #pragma unroll
    for (int rt = 0; rt < 4; ++rt) ba[rt] = *(s16x8*)&As[rt*16 + lm][k0];
    #pragma unroll
    for (int i = 0; i < 2; ++i)
      #pragma unroll
      for (int rt = 0; rt < 4; ++rt){
        acc[i][rt] = __builtin_amdgcn_mfma_f32_16x16x32_bf16(awh[i], ba[rt], acc[i][rt], 0, 0, 0);
        acc[i][rt] = __builtin_amdgcn_mfma_f32_16x16x32_bf16(awl[i], ba[rt], acc[i][rt], 0, 0, 0);
      }
  }
  // epilogue: D row=e(quad*4+reg), col=row(lm)
  #pragma unroll
  for (int i = 0; i < 2; ++i){
    int e0 = (2*w+i)*16 + quad*4;
    f4 bv = *(const f4*)&bvec[e0];
    if (wsel == 0){
      // mapped mode: hi/lo planes, chunked [bp][dc][m][32]
      u16* mh = (u16*)outv;
      u16* ml = mh + 16777216;
      int dc = e0 >> 5, ec = e0 & 31;
      #pragma unroll
      for (int rt = 0; rt < 4; ++rt){
        int row = rowbase + rt*16 + lm;
        int bp = row >> 8, m = row & 255;
        f4 o = acc[i][rt] + bv;
        float fv[4] = {o.x, o.y, o.z, o.w};
        u16 hh[4], ll[4];
        #pragma unroll
        for (int e = 0; e < 4; ++e){
          u16 h = f2b(fv[e]);
          hh[e] = h; ll[e] = f2b(fv[e] - b2f(h));
        }
        int off = ((bp*4 + dc)*256 + m)*32 + ec;
        *(uint2*)&mh[off] = *(uint2*)&hh[0];
        *(uint2*)&ml[off] = *(uint2*)&ll[0];
      }
    } else {
      float* outp = (float*)outv;
      f4 sv = (f4)0.f, qv = (f4)0.f;
      #pragma unroll
      for (int rt = 0; rt < 4; ++rt){
        int row = rowbase + rt*16 + lm;
        f4 o = acc[i][rt] + bv;
        *(f4*)&outp[row*128 + e0] = o;
        sv += o; qv += o*o;
      }
      if (do_stats){
        #pragma unroll
        for (int m = 1; m < 16; m <<= 1){
          sv.x+=__shfl_xor(sv.x,m); sv.y+=__shfl_xor(sv.y,m); sv.z+=__shfl_xor(sv.z,m); sv.w+=__shfl_xor(sv.w,m);
          qv.x+=__shfl_xor(qv.x,m); qv.y+=__shfl_xor(qv.y,m); qv.z+=__shfl_xor(qv.z,m); qv.w+=__shfl_xor(qv.w,m);
        }
        if (lm == 0){
          *(f4*)&g_part[bid][e0]       = sv;
          *(f4*)&g_part[bid][128 + e0] = qv;
        }
      }
    }
  }
}

// ---------------- fused adj+agg MFMA; spa is PRE-ACTIVATED (by gemm0 write-back) ----------------
__global__ __launch_bounds__(256) void k_adjagg(const u16* __restrict__ mh,
                                                const u16* __restrict__ ml,
                                                const u16* __restrict__ spa,
                                                u16* __restrict__ agg){
  __shared__ __align__(16) char smem[52224];
  u16 (*mbh)[40]   = (u16(*)[40])(smem);
  u16 (*mbl)[40]   = (u16(*)[40])(smem + 20480);
  u16 (*Ps)[264]   = (u16(*)[264])(smem);            // [64][264] = 33792 B
  u16 (*spasT)[72] = (u16(*)[72])(smem + 33792);     // [128][72] = 18432 B
  // XCD-aware remap: 4 nt-blocks of one bp land consecutively on the same XCD
  const int rb = blockIdx.x;
  const int vb = (rb & 7)*256 + (rb >> 3);
  const int bp = vb >> 2;
  const int nt = vb & 3;
  const int tid = threadIdx.x;
  const int w = tid >> 6, l = tid & 63, quad = l >> 4, lm = l & 15;

  // ---- phase 1: S rows (wave w -> row-tile w) x all 256 cols, hi/lo 3-term ----
  f4 sacc[16];
  #pragma unroll
  for (int ct = 0; ct < 16; ++ct) sacc[ct] = (f4)0.f;

  for (int dc = 0; dc < 4; ++dc){
    __syncthreads();
    { // pure copy staging from pre-split chunked planes (coalesced, conflict-free)
      const u16* srch = mh + ((bp*4 + dc) << 13);
      const u16* srcl = ml + ((bp*4 + dc) << 13);
      int m0 = tid >> 2, seg = (tid & 3)*8;
      #pragma unroll
      for (int r = 0; r < 4; ++r){
        int m = m0 + r*64;
        *(uint4*)&mbh[m][seg] = *(const uint4*)&srch[m*32 + seg];
        *(uint4*)&mbl[m][seg] = *(const uint4*)&srcl[m*32 + seg];
      }
    }
    __syncthreads();
    s16x8 amh = *(s16x8*)&mbh[nt*64 + w*16 + lm][quad*8];
    s16x8 aml = *(s16x8*)&mbl[nt*64 + w*16 + lm][quad*8];
    #pragma unroll
    for (int ct = 0; ct < 16; ++ct){
      s16x8 bmh = *(s16x8*)&mbh[ct*16 + lm][quad*8];
      s16x8 bml = *(s16x8*)&mbl[ct*16 + lm][quad*8];
      sacc[ct] = __builtin_amdgcn_mfma_f32_16x16x32_bf16(amh, bmh, sacc[ct], 0, 0, 0);
      sacc[ct] = __builtin_amdgcn_mfma_f32_16x16x32_bf16(amh, bml, sacc[ct], 0, 0, 0);
      sacc[ct] = __builtin_amdgcn_mfma_f32_16x16x32_bf16(aml, bmh, sacc[ct], 0, 0, 0);
    }
  }
  __syncthreads();   // all mbuf reads done; Ps may now overlay

  // ---- softmax (regs only) -> Ps[row][m] bf16 ----
  #pragma unroll
  for (int r = 0; r < 4; ++r){
    int rowg = nt*64 + w*16 + quad*4 + r;
    float v[16]; float mx = -3.0e38f;
    #pragma unroll
    for (int ct = 0; ct < 16; ++ct){
      float t = sacc[ct][r];
      if (ct*16 + lm == rowg) t -= 1e8f;
      t = lrelu(t);
      v[ct] = t; mx = fmaxf(mx, t);
    }
    #pragma unroll
    for (int m = 1; m < 16; m <<= 1) mx = fmaxf(mx, __shfl_xor(mx, m));
    float sum = 0.f;
    #pragma unroll
    for (int ct = 0; ct < 16; ++ct){ float e = __expf(v[ct] - mx); v[ct] = e; sum += e; }
    #pragma unroll
    for (int m = 1; m < 16; m <<= 1) sum += __shfl_xor(sum, m);
    float inv = 1.0f / sum;
    #pragma unroll
    for (int ct = 0; ct < 16; ++ct)
      Ps[w*16 + quad*4 + r][ct*16 + lm] = f2b(v[ct] * inv);
  }

  // ---- phase 2: agg = P @ spa (+ spa for +I). spa already activated; pure copy transpose. ----
  f4 acc2[2][4];
  #pragma unroll
  for (int i = 0; i < 2; ++i)
    #pragma unroll
    for (int rt = 0; rt < 4; ++rt) acc2[i][rt] = (f4)0.f;

  for (int mc2 = 0; mc2 < 4; ++mc2){
    __syncthreads();
    { // transpose-stage spa[64 m][128 d] -> spasT[128][72] (no conversion)
      int mlo = tid & 63;
      int db = (tid >> 6)*8;
      const u16* ps = spa + (bp*256 + mc2*64 + mlo)*128;
      #pragma unroll
      for (int r = 0; r < 4; ++r){
        int d0 = db + r*32;
        uint4 v = *(const uint4*)(ps + d0);
        u16 h[8]; *(uint4*)&h[0] = v;
        #pragma unroll
        for (int j = 0; j < 8; ++j) spasT[d0+j][mlo] = h[j];
      }
    }
    __syncthreads();
    #pragma unroll
    for (int ks = 0; ks < 2; ++ks){
      int m0 = ks*32 + quad*8;
      s16x8 afs[2], bfp[4];
      #pragma unroll
      for (int i = 0; i < 2; ++i) afs[i] = *(s16x8*)&spasT[(2*w+i)*16 + lm][m0];
      #pragma unroll
      for (int rt = 0; rt < 4; ++rt) bfp[rt] = *(s16x8*)&Ps[rt*16 + lm][mc2*64 + m0];
      #pragma unroll
      for (int i = 0; i < 2; ++i)
        #pragma unroll
        for (int rt = 0; rt < 4; ++rt)
          acc2[i][rt] = __builtin_amdgcn_mfma_f32_16x16x32_bf16(afs[i], bfp[rt], acc2[i][rt], 0, 0, 0);
    }
  }
  // store: D row=d(quad*4+reg), col=row(lm); +I term direct (spa pre-activated)
  #pragma unroll
  for (int i = 0; i < 2; ++i){
    int d0 = (2*w+i)*16 + quad*4;
    #pragma unroll
    for (int rt = 0; rt < 4; ++rt){
      int grow = bp*256 + nt*64 + rt*16 + lm;
      uint2 sp = *(const uint2*)&spa[grow*128 + d0];
      f4 a = acc2[i][rt];
      a.x += b2f((u16)(sp.x & 0xffff)); a.y += b2f((u16)(sp.x >> 16));
      a.z += b2f((u16)(sp.y & 0xffff)); a.w += b2f((u16)(sp.y >> 16));
      uint2 p; p.x = pk(a.x, a.y); p.y = pk(a.z, a.w);
      *(uint2*)&agg[grow*128 + d0] = p;
    }
  }
}

// ---------------- final BN + leaky, in place ----------------
__global__ void k_bnout(float* __restrict__ outp){
  int idx = blockIdx.x*256 + threadIdx.x;
  int flat = idx*4;
  int o = flat & 127;
  float4 v = *(const float4*)(outp + flat);
  v.x = lrelu(fmaf(v.x, g_sb[2][0][o+0], g_sb[2][1][o+0]));
  v.y = lrelu(fmaf(v.y, g_sb[2][0][o+1], g_sb[2][1][o+1]));
  v.z = lrelu(fmaf(v.z, g_sb[2][0][o+2], g_sb[2][1][o+2]));
  v.w = lrelu(fmaf(v.w, g_sb[2][0][o+3], g_sb[2][1][o+3]));
  *(float4*)(outp + flat) = v;
}

extern "C" void kernel_launch(void* const* d_in, const int* in_sizes, int n_in,
                              void* d_out, int out_size, void* d_ws, size_t ws_size,
                              hipStream_t stream) {
  const float* x    = (const float*)d_in[0];
  const float* w1   = (const float*)d_in[1];
  const float* bn1g = (const float*)d_in[2];
  const float* bn1b = (const float*)d_in[3];
  const float* w2   = (const float*)d_in[4];
  const float* bn2g = (const float*)d_in[5];
  const float* bn2b = (const float*)d_in[6];
  const float* mapw = (const float*)d_in[7];
  const float* mapb = (const float*)d_in[8];
  const float* thw  = (const float*)d_in[9];
  const float* thb  = (const float*)d_in[10];
  const float* bnSg = (const float*)d_in[11];
  const float* bnSb = (const float*)d_in[12];
  float* outp = (float*)d_out;

  // ws (64 MB): spa (16M bf16; pre-BN2 until gemm0 activates in place) + agg (16M bf16)
  u16* spa = (u16*)d_ws;
  u16* agg = spa + 16777216;

  // d_out scratch phases: y1hl (64 MB) -> mapped hi/lo planes (mh 32MB + ml 32MB) -> out fp32
  u16* y1hl = (u16*)d_out;
  u16* mh   = (u16*)d_out;
  u16* ml   = mh + 16777216;

  k_zero<<<3, 256, 0, stream>>>();
  k_prepw<<<416, 256, 0, stream>>>(w1, w2, mapw, thw);
  k_conv1<<<2048, 256, 0, stream>>>(x, y1hl);
  k_reduce<<<16, 256, 0, stream>>>(0);
  k_finalize<<<1, 128, 0, stream>>>(bn1g, bn1b, 0);
  k_conv2<<<2048, 256, 0, stream>>>(y1hl, spa);
  k_reduce<<<16, 256, 0, stream>>>(1);
  k_finalize<<<1, 128, 0, stream>>>(bn2g, bn2b, 1);
  k_gemm128b<<<2048, 256, 0, stream>>>(spa, spa, mapb, (void*)mh, 0, 0);
  k_adjagg<<<2048, 256, 0, stream>>>(mh, ml, spa, agg);
  k_gemm128b<<<2048, 256, 0, stream>>>(agg, agg, thb, (void*)outp, 1, 1);
  k_reduce<<<16, 256, 0, stream>>>(2);
  k_finalize<<<1, 128, 0, stream>>>(bnSg, bnSb, 2);
  k_bnout<<<16384, 256, 0, stream>>>(outp);
}